// Round 3
// baseline (739.572 us; speedup 1.0000x reference)
//
#include <hip/hip_runtime.h>

#define N_ROWS 131072
#define DIM 64
#define KCODES 1024
#define CHUNK 256          // codes staged per LDS chunk (64 KiB as fp32)
#define BLOCK 256          // one row per thread
#define NBLOCKS (N_ROWS / BLOCK)   // 512

// ---------------------------------------------------------------------------
// numpy pairwise sum of squares over 64 contiguous floats, bit-exact:
// products rounded fp32 individually (flat*flat temp array), then numpy's
// 8-accumulator pairwise scheme with tree combine. __f*_rn intrinsics forbid
// FMA contraction / reassociation.
// ---------------------------------------------------------------------------
__device__ __forceinline__ float np_pairwise_sq64(const float* v) {
    float r[8];
#pragma unroll
    for (int j = 0; j < 8; ++j) r[j] = __fmul_rn(v[j], v[j]);
#pragma unroll
    for (int i = 8; i < 64; i += 8)
#pragma unroll
        for (int j = 0; j < 8; ++j)
            r[j] = __fadd_rn(r[j], __fmul_rn(v[i + j], v[i + j]));
    return __fadd_rn(
        __fadd_rn(__fadd_rn(r[0], r[1]), __fadd_rn(r[2], r[3])),
        __fadd_rn(__fadd_rn(r[4], r[5]), __fadd_rn(r[6], r[7])));
}

// ---------------------------------------------------------------------------
// Kernel 0: zero histogram + b_sq per code via the numpy-replicated scheme.
// ---------------------------------------------------------------------------
__global__ void vq_prep(const float* __restrict__ emb,
                        int* __restrict__ hist,
                        float* __restrict__ bsqf) {
    int k = blockIdx.x * blockDim.x + threadIdx.x;   // 0..1023
    if (k >= KCODES) return;
    hist[k] = 0;
    float e[DIM];
    const float4* src = reinterpret_cast<const float4*>(emb + (size_t)k * DIM);
#pragma unroll
    for (int i = 0; i < DIM / 4; ++i) {
        float4 v = src[i];
        e[i * 4 + 0] = v.x; e[i * 4 + 1] = v.y;
        e[i * 4 + 2] = v.z; e[i * 4 + 3] = v.w;
    }
    bsqf[k] = np_pairwise_sq64(e);
}

// ---------------------------------------------------------------------------
// Kernel 1: per-row argmin replicating the reference's fp32 rounding chain:
//   d = fl32( fl32(a_sq - fl32(2*dot_exact)) + b_sq )
// with a_sq/b_sq numpy-pairwise fp32 and dot in fp64 (effectively exact).
// Monotone rounding => only ties matter; strict '<' keeps the first index,
// matching np.argmin.
// ---------------------------------------------------------------------------
__global__ __launch_bounds__(BLOCK, 2)
void vq_main(const float* __restrict__ x,
             const float* __restrict__ emb,
             const float* __restrict__ bsqf,
             float* __restrict__ qout,
             float* __restrict__ idxout,
             int* __restrict__ hist,
             float* __restrict__ partials) {
    __shared__ float lds[CHUNK * DIM];   // 64 KiB
    __shared__ float red[BLOCK];

    const int row = blockIdx.x * BLOCK + threadIdx.x;

    // Load row (fp32), compute a_sq bit-exactly, then keep fp64 copy for dot.
    float af[DIM];
    {
        const float4* xr = reinterpret_cast<const float4*>(x + (size_t)row * DIM);
#pragma unroll
        for (int i = 0; i < DIM / 4; ++i) {
            float4 v = xr[i];
            af[i * 4 + 0] = v.x; af[i * 4 + 1] = v.y;
            af[i * 4 + 2] = v.z; af[i * 4 + 3] = v.w;
        }
    }
    const float a_sq = np_pairwise_sq64(af);

    double ad[DIM];
#pragma unroll
    for (int i = 0; i < DIM; ++i) ad[i] = (double)af[i];

    float best = 3.402823466e+38f;
    int bidx = 0;

    for (int c0 = 0; c0 < KCODES; c0 += CHUNK) {
        __syncthreads();
        {   // stage CHUNK codes (coalesced float4 copy)
            const float4* src = reinterpret_cast<const float4*>(emb + (size_t)c0 * DIM);
            float4* dst = reinterpret_cast<float4*>(lds);
#pragma unroll
            for (int i = 0; i < (CHUNK * DIM / 4) / BLOCK; ++i)
                dst[threadIdx.x + i * BLOCK] = src[threadIdx.x + i * BLOCK];
        }
        __syncthreads();

        for (int c = 0; c < CHUNK; ++c) {
            const float* e = &lds[c * DIM];
            double acc0 = 0.0, acc1 = 0.0, acc2 = 0.0, acc3 = 0.0;
#pragma unroll
            for (int d = 0; d < DIM; d += 4) {
                acc0 = fma(ad[d + 0], (double)e[d + 0], acc0);
                acc1 = fma(ad[d + 1], (double)e[d + 1], acc1);
                acc2 = fma(ad[d + 2], (double)e[d + 2], acc2);
                acc3 = fma(ad[d + 3], (double)e[d + 3], acc3);
            }
            double dot = (acc0 + acc1) + (acc2 + acc3);
            // Reference chain: ab = fl32(2*dot); d = fl32(fl32(a_sq-ab)+b_sq)
            float ab = (float)(2.0 * dot);
            float dist = __fadd_rn(__fsub_rn(a_sq, ab), bsqf[c0 + c]);
            if (dist < best) { best = dist; bidx = c0 + c; }
        }
    }

    // Quantized output row + per-thread squared-error sum.
    float lsum0 = 0.f, lsum1 = 0.f;
    {
        const float4* q = reinterpret_cast<const float4*>(emb + (size_t)bidx * DIM);
        float4* qo = reinterpret_cast<float4*>(qout + (size_t)row * DIM);
#pragma unroll
        for (int i = 0; i < DIM / 4; ++i) {
            float4 v = q[i];
            qo[i] = v;
            float dx = v.x - af[i * 4 + 0];
            float dy = v.y - af[i * 4 + 1];
            float dz = v.z - af[i * 4 + 2];
            float dw = v.w - af[i * 4 + 3];
            lsum0 = fmaf(dx, dx, lsum0);
            lsum1 = fmaf(dy, dy, lsum1);
            lsum0 = fmaf(dz, dz, lsum0);
            lsum1 = fmaf(dw, dw, lsum1);
        }
    }
    idxout[row] = (float)bidx;
    atomicAdd(&hist[bidx], 1);

    // Deterministic per-block tree reduction of the loss.
    __syncthreads();
    red[threadIdx.x] = lsum0 + lsum1;
    __syncthreads();
    for (int off = BLOCK / 2; off > 0; off >>= 1) {
        if (threadIdx.x < off) red[threadIdx.x] += red[threadIdx.x + off];
        __syncthreads();
    }
    if (threadIdx.x == 0) partials[blockIdx.x] = red[0];
}

// ---------------------------------------------------------------------------
// Kernel 2: perplexity from histogram (fp64) + final loss reduction.
// ---------------------------------------------------------------------------
__global__ void vq_final(const int* __restrict__ hist,
                         const float* __restrict__ partials,
                         float* __restrict__ out2) {
    __shared__ double sh[KCODES];
    __shared__ float sl[NBLOCKS];
    int t = threadIdx.x;

    double p = (double)hist[t] * (1.0 / (double)N_ROWS);
    sh[t] = p * log(p + 1e-10);
    if (t < NBLOCKS) sl[t] = partials[t];
    __syncthreads();

    for (int off = KCODES / 2; off > 0; off >>= 1) {
        if (t < off) sh[t] += sh[t + off];
        __syncthreads();
    }
    for (int off = NBLOCKS / 2; off > 0; off >>= 1) {
        if (t < off) sl[t] += sl[t + off];
        __syncthreads();
    }
    if (t == 0) {
        out2[0] = (float)exp(-sh[0]);
        // vq_loss = commitment + 0.25*codebook = 1.25 * mean((q-x)^2)
        out2[1] = 1.25f * sl[0] * (1.0f / (float)(N_ROWS * DIM));
    }
}

// ---------------------------------------------------------------------------
extern "C" void kernel_launch(void* const* d_in, const int* in_sizes, int n_in,
                              void* d_out, int out_size, void* d_ws, size_t ws_size,
                              hipStream_t stream) {
    const float* x   = (const float*)d_in[0];   // [131072, 64]
    const float* emb = (const float*)d_in[1];   // [1024, 64]
    float* out = (float*)d_out;

    // ws layout: int hist[1024] @0 | float bsqf[1024] @4096 | partials @8192
    int*   hist     = (int*)d_ws;
    float* bsqf     = (float*)((char*)d_ws + 4096);
    float* partials = (float*)((char*)d_ws + 8192);

    float* qout    = out;                       // 8388608
    float* idxout  = out + 8388608;             // 131072
    float* scalars = out + 8388608 + 131072;    // perplexity, vq_loss

    vq_prep <<<KCODES / 256, 256, 0, stream>>>(emb, hist, bsqf);
    vq_main <<<NBLOCKS, BLOCK, 0, stream>>>(x, emb, bsqf, qout, idxout, hist, partials);
    vq_final<<<1, KCODES, 0, stream>>>(hist, partials, scalars);
}

// Round 4
// 444.487 us; speedup vs baseline: 1.6639x; 1.6639x over previous
//
#include <hip/hip_runtime.h>
#include <float.h>

#define N_ROWS 131072
#define DIM 64
#define KCODES 1024
#define CHUNK 256                    // codes per LDS stage (64 KiB)
#define BLOCKA 256                   // threads, pass A
#define ROWS_PER_BLOCK 512           // BLOCKA * 2 rows (R=2 per thread)
#define NBLOCKA (N_ROWS / ROWS_PER_BLOCK)   // 256
#define BLOCKC 256
#define NBLOCKC (N_ROWS / BLOCKC)           // 512
#define TAU 4.0e-4f

// ---------------------------------------------------------------------------
// numpy pairwise sum of squares over 64 floats, bit-exact vs np.sum(v*v):
// fp32-rounded products, 8 strided accumulators, tree combine.
// ---------------------------------------------------------------------------
__device__ __forceinline__ float np_pairwise_sq64(const float* v) {
    float r[8];
#pragma unroll
    for (int j = 0; j < 8; ++j) r[j] = __fmul_rn(v[j], v[j]);
#pragma unroll
    for (int i = 8; i < 64; i += 8)
#pragma unroll
        for (int j = 0; j < 8; ++j)
            r[j] = __fadd_rn(r[j], __fmul_rn(v[i + j], v[i + j]));
    return __fadd_rn(
        __fadd_rn(__fadd_rn(r[0], r[1]), __fadd_rn(r[2], r[3])),
        __fadd_rn(__fadd_rn(r[4], r[5]), __fadd_rn(r[6], r[7])));
}

// ---------------------------------------------------------------------------
// Kernel 0: zero hist + ambiguous counter; b_sq per code (numpy scheme).
// ---------------------------------------------------------------------------
__global__ void vq_prep(const float* __restrict__ emb,
                        int* __restrict__ hist,
                        float* __restrict__ bsqf,
                        int* __restrict__ amb_count) {
    int k = blockIdx.x * blockDim.x + threadIdx.x;
    if (k == 0) *amb_count = 0;
    if (k >= KCODES) return;
    hist[k] = 0;
    float e[DIM];
    const float4* src = reinterpret_cast<const float4*>(emb + (size_t)k * DIM);
#pragma unroll
    for (int i = 0; i < DIM / 4; ++i) {
        float4 v = src[i];
        e[i * 4 + 0] = v.x; e[i * 4 + 1] = v.y;
        e[i * 4 + 2] = v.z; e[i * 4 + 3] = v.w;
    }
    bsqf[k] = np_pairwise_sq64(e);
}

// ---------------------------------------------------------------------------
// Pass A: fast fp32 scorer. 2 rows/thread, codebook chunks in LDS (broadcast
// reads). Tracks best/second/index; flags rows with gap <= TAU for the exact
// pass. Writes provisional indices as floats into idxout.
// ---------------------------------------------------------------------------
__global__ __launch_bounds__(BLOCKA, 1)
void vq_fast(const float* __restrict__ x,
             const float* __restrict__ emb,
             const float* __restrict__ bsqf,
             float* __restrict__ idxout,
             int* __restrict__ amb_count,
             int* __restrict__ amb_list) {
    __shared__ float lds[CHUNK * DIM];   // 64 KiB

    const int t = threadIdx.x;
    const int base = blockIdx.x * ROWS_PER_BLOCK;
    const int row0 = base + t;
    const int row1 = base + t + BLOCKA;

    float a0[DIM], a1[DIM];
    {
        const float4* r0 = reinterpret_cast<const float4*>(x + (size_t)row0 * DIM);
        const float4* r1 = reinterpret_cast<const float4*>(x + (size_t)row1 * DIM);
#pragma unroll
        for (int i = 0; i < DIM / 4; ++i) {
            float4 v0 = r0[i], v1 = r1[i];
            a0[i * 4 + 0] = v0.x; a0[i * 4 + 1] = v0.y;
            a0[i * 4 + 2] = v0.z; a0[i * 4 + 3] = v0.w;
            a1[i * 4 + 0] = v1.x; a1[i * 4 + 1] = v1.y;
            a1[i * 4 + 2] = v1.z; a1[i * 4 + 3] = v1.w;
        }
    }

    float best0 = FLT_MAX, sec0 = FLT_MAX;
    float best1 = FLT_MAX, sec1 = FLT_MAX;
    int b0 = 0, b1 = 0;

    for (int c0 = 0; c0 < KCODES; c0 += CHUNK) {
        __syncthreads();
        {   // stage CHUNK codes, coalesced float4
            const float4* src = reinterpret_cast<const float4*>(emb + (size_t)c0 * DIM);
            float4* dst = reinterpret_cast<float4*>(lds);
#pragma unroll
            for (int i = 0; i < (CHUNK * DIM / 4) / BLOCKA; ++i)
                dst[t + i * BLOCKA] = src[t + i * BLOCKA];
        }
        __syncthreads();

#pragma unroll 2
        for (int c = 0; c < CHUNK; ++c) {
            const float4* e4 = reinterpret_cast<const float4*>(&lds[c * DIM]);
            float p00 = 0.f, p01 = 0.f, p02 = 0.f, p03 = 0.f;
            float p10 = 0.f, p11 = 0.f, p12 = 0.f, p13 = 0.f;
#pragma unroll
            for (int i = 0; i < DIM / 4; ++i) {
                float4 e = e4[i];
                p00 = fmaf(a0[i * 4 + 0], e.x, p00);
                p01 = fmaf(a0[i * 4 + 1], e.y, p01);
                p02 = fmaf(a0[i * 4 + 2], e.z, p02);
                p03 = fmaf(a0[i * 4 + 3], e.w, p03);
                p10 = fmaf(a1[i * 4 + 0], e.x, p10);
                p11 = fmaf(a1[i * 4 + 1], e.y, p11);
                p12 = fmaf(a1[i * 4 + 2], e.z, p12);
                p13 = fmaf(a1[i * 4 + 3], e.w, p13);
            }
            float bq = bsqf[c0 + c];
            float s0v = fmaf(-2.0f, (p00 + p01) + (p02 + p03), bq);
            float s1v = fmaf(-2.0f, (p10 + p11) + (p12 + p13), bq);

            sec0 = fminf(sec0, fmaxf(s0v, best0));
            b0 = (s0v < best0) ? (c0 + c) : b0;
            best0 = fminf(best0, s0v);

            sec1 = fminf(sec1, fmaxf(s1v, best1));
            b1 = (s1v < best1) ? (c0 + c) : b1;
            best1 = fminf(best1, s1v);
        }
    }

    idxout[row0] = (float)b0;
    idxout[row1] = (float)b1;
    if (sec0 - best0 <= TAU) { int p = atomicAdd(amb_count, 1); amb_list[p] = row0; }
    if (sec1 - best1 <= TAU) { int p = atomicAdd(amb_count, 1); amb_list[p] = row1; }
}

// ---------------------------------------------------------------------------
// Pass B: exact rescan for ambiguous rows — one wave per row, replicating the
// validated reference chain: np-pairwise a_sq/b_sq (fp32), fp64 dot,
// d = fl32(fl32(a_sq - fl32(2*dot)) + b_sq), np.argmin first-index tie-break.
// ---------------------------------------------------------------------------
__global__ void vq_exact(const float* __restrict__ x,
                         const float* __restrict__ emb,
                         const float* __restrict__ bsqf,
                         const int* __restrict__ amb_count,
                         const int* __restrict__ amb_list,
                         float* __restrict__ idxout) {
    const int lane = threadIdx.x;      // 64 lanes = 1 wave
    const int cnt = *amb_count;

    for (int i = blockIdx.x; i < cnt; i += gridDim.x) {
        const int row = amb_list[i];
        float af[DIM];
        const float4* xr = reinterpret_cast<const float4*>(x + (size_t)row * DIM);
#pragma unroll
        for (int j = 0; j < DIM / 4; ++j) {
            float4 v = xr[j];
            af[j * 4 + 0] = v.x; af[j * 4 + 1] = v.y;
            af[j * 4 + 2] = v.z; af[j * 4 + 3] = v.w;
        }
        const float a_sq = np_pairwise_sq64(af);

        float best = FLT_MAX;
        int bidx = KCODES;
        for (int c = lane; c < KCODES; c += 64) {
            const float* e = emb + (size_t)c * DIM;
            double acc0 = 0.0, acc1 = 0.0, acc2 = 0.0, acc3 = 0.0;
#pragma unroll
            for (int d = 0; d < DIM; d += 4) {
                acc0 = fma((double)af[d + 0], (double)e[d + 0], acc0);
                acc1 = fma((double)af[d + 1], (double)e[d + 1], acc1);
                acc2 = fma((double)af[d + 2], (double)e[d + 2], acc2);
                acc3 = fma((double)af[d + 3], (double)e[d + 3], acc3);
            }
            double dot = (acc0 + acc1) + (acc2 + acc3);
            float ab = (float)(2.0 * dot);
            float dist = __fadd_rn(__fsub_rn(a_sq, ab), bsqf[c]);
            if (dist < best) { best = dist; bidx = c; }
        }
        // cross-lane argmin, ties -> lower index (np.argmin semantics)
#pragma unroll
        for (int off = 32; off > 0; off >>= 1) {
            float ob = __shfl_xor(best, off);
            int   oi = __shfl_xor(bidx, off);
            if (ob < best || (ob == best && oi < bidx)) { best = ob; bidx = oi; }
        }
        if (lane == 0) idxout[row] = (float)bidx;
    }
}

// ---------------------------------------------------------------------------
// Pass C: finalize — gather quantized rows, histogram, deterministic loss tree.
// ---------------------------------------------------------------------------
__global__ __launch_bounds__(BLOCKC, 2)
void vq_finalize(const float* __restrict__ x,
                 const float* __restrict__ emb,
                 const float* __restrict__ idxout,
                 float* __restrict__ qout,
                 int* __restrict__ hist,
                 float* __restrict__ partials) {
    __shared__ float red[BLOCKC];
    const int row = blockIdx.x * BLOCKC + threadIdx.x;
    const int k = (int)idxout[row];

    const float4* xr = reinterpret_cast<const float4*>(x + (size_t)row * DIM);
    const float4* q  = reinterpret_cast<const float4*>(emb + (size_t)k * DIM);
    float4* qo = reinterpret_cast<float4*>(qout + (size_t)row * DIM);

    float lsum0 = 0.f, lsum1 = 0.f;
#pragma unroll
    for (int i = 0; i < DIM / 4; ++i) {
        float4 v = q[i];
        float4 a = xr[i];
        qo[i] = v;
        float dx = v.x - a.x, dy = v.y - a.y;
        float dz = v.z - a.z, dw = v.w - a.w;
        lsum0 = fmaf(dx, dx, lsum0);
        lsum1 = fmaf(dy, dy, lsum1);
        lsum0 = fmaf(dz, dz, lsum0);
        lsum1 = fmaf(dw, dw, lsum1);
    }
    atomicAdd(&hist[k], 1);

    __syncthreads();
    red[threadIdx.x] = lsum0 + lsum1;
    __syncthreads();
    for (int off = BLOCKC / 2; off > 0; off >>= 1) {
        if (threadIdx.x < off) red[threadIdx.x] += red[threadIdx.x + off];
        __syncthreads();
    }
    if (threadIdx.x == 0) partials[blockIdx.x] = red[0];
}

// ---------------------------------------------------------------------------
// Kernel 4: perplexity (fp64) + final loss reduction.
// ---------------------------------------------------------------------------
__global__ void vq_final(const int* __restrict__ hist,
                         const float* __restrict__ partials,
                         float* __restrict__ out2) {
    __shared__ double sh[KCODES];
    __shared__ float sl[NBLOCKC];
    int t = threadIdx.x;

    double p = (double)hist[t] * (1.0 / (double)N_ROWS);
    sh[t] = p * log(p + 1e-10);
    if (t < NBLOCKC) sl[t] = partials[t];
    __syncthreads();

    for (int off = KCODES / 2; off > 0; off >>= 1) {
        if (t < off) sh[t] += sh[t + off];
        __syncthreads();
    }
    for (int off = NBLOCKC / 2; off > 0; off >>= 1) {
        if (t < off) sl[t] += sl[t + off];
        __syncthreads();
    }
    if (t == 0) {
        out2[0] = (float)exp(-sh[0]);
        out2[1] = 1.25f * sl[0] * (1.0f / (float)(N_ROWS * DIM));
    }
}

// ---------------------------------------------------------------------------
extern "C" void kernel_launch(void* const* d_in, const int* in_sizes, int n_in,
                              void* d_out, int out_size, void* d_ws, size_t ws_size,
                              hipStream_t stream) {
    const float* x   = (const float*)d_in[0];   // [131072, 64]
    const float* emb = (const float*)d_in[1];   // [1024, 64]
    float* out = (float*)d_out;

    // ws: hist[1024]@0 | bsqf[1024]@4096 | partials[512]@8192 |
    //     amb_count@10240 | amb_list[131072]@12288  (~537 KB total)
    int*   hist      = (int*)d_ws;
    float* bsqf      = (float*)((char*)d_ws + 4096);
    float* partials  = (float*)((char*)d_ws + 8192);
    int*   amb_count = (int*)((char*)d_ws + 10240);
    int*   amb_list  = (int*)((char*)d_ws + 12288);

    float* qout    = out;                       // 8388608
    float* idxout  = out + 8388608;             // 131072
    float* scalars = out + 8388608 + 131072;    // perplexity, vq_loss

    vq_prep    <<<KCODES / 256, 256, 0, stream>>>(emb, hist, bsqf, amb_count);
    vq_fast    <<<NBLOCKA, BLOCKA, 0, stream>>>(x, emb, bsqf, idxout, amb_count, amb_list);
    vq_exact   <<<256, 64, 0, stream>>>(x, emb, bsqf, amb_count, amb_list, idxout);
    vq_finalize<<<NBLOCKC, BLOCKC, 0, stream>>>(x, emb, idxout, qout, hist, partials);
    vq_final   <<<1, KCODES, 0, stream>>>(hist, partials, scalars);
}

// Round 5
// 295.005 us; speedup vs baseline: 2.5070x; 1.5067x over previous
//
#include <hip/hip_runtime.h>
#include <float.h>

#define N_ROWS 131072
#define DIM 64
#define KCODES 1024
#define TAU 1.0e-3f
#define AMB_MAX 32768
#define BLOCKC 256
#define NBLOCKC (N_ROWS / BLOCKC)   // 512

typedef __attribute__((ext_vector_type(8))) short short8;
typedef __attribute__((ext_vector_type(4))) float f32x4;

// bf16 round-to-nearest-even split helpers
__device__ __forceinline__ unsigned short f2bf_rne(float x) {
    unsigned int u = __float_as_uint(x);
    unsigned int r = u + 0x7FFFu + ((u >> 16) & 1u);
    return (unsigned short)(r >> 16);
}
__device__ __forceinline__ float bf2f(unsigned short h) {
    return __uint_as_float(((unsigned int)h) << 16);
}

// numpy pairwise sum of squares over 64 floats (bit-exact vs np.sum(v*v))
__device__ __forceinline__ float np_pairwise_sq64(const float* v) {
    float r[8];
#pragma unroll
    for (int j = 0; j < 8; ++j) r[j] = __fmul_rn(v[j], v[j]);
#pragma unroll
    for (int i = 8; i < 64; i += 8)
#pragma unroll
        for (int j = 0; j < 8; ++j)
            r[j] = __fadd_rn(r[j], __fmul_rn(v[i + j], v[i + j]));
    return __fadd_rn(
        __fadd_rn(__fadd_rn(r[0], r[1]), __fadd_rn(r[2], r[3])),
        __fadd_rn(__fadd_rn(r[4], r[5]), __fadd_rn(r[6], r[7])));
}

// ---------------------------------------------------------------------------
// Prep: zero hist/amb, np-exact b_sq, and pack E as bf16 hi/lo in MFMA
// frag order: epack[ct(64)][lvl(2)][kt(2)][lane(64)][j(8)] ushort.
// lane for element k of code c: ((k&31)>>3)*16 + (c&15); j = k&7; kt = k>>5.
// ---------------------------------------------------------------------------
__global__ void vq_prep(const float* __restrict__ emb,
                        int* __restrict__ hist,
                        float* __restrict__ bsqf,
                        int* __restrict__ amb_count,
                        unsigned short* __restrict__ epack) {
    int c = blockIdx.x * blockDim.x + threadIdx.x;   // 0..1023
    if (c == 0) *amb_count = 0;
    if (c >= KCODES) return;
    hist[c] = 0;
    float e[DIM];
    const float4* src = reinterpret_cast<const float4*>(emb + (size_t)c * DIM);
#pragma unroll
    for (int i = 0; i < DIM / 4; ++i) {
        float4 v = src[i];
        e[i * 4 + 0] = v.x; e[i * 4 + 1] = v.y;
        e[i * 4 + 2] = v.z; e[i * 4 + 3] = v.w;
    }
    bsqf[c] = np_pairwise_sq64(e);

    const int ct = c >> 4, col = c & 15;
#pragma unroll
    for (int k = 0; k < DIM; ++k) {
        unsigned short h = f2bf_rne(e[k]);
        unsigned short l = f2bf_rne(e[k] - bf2f(h));
        int kt = k >> 5;
        int lane = (((k & 31) >> 3) << 4) | col;
        int j = k & 7;
        // idx = (((ct*2 + lvl)*2 + kt)*64 + lane)*8 + j
        epack[(((size_t)(ct * 2 + 0) * 2 + kt) * 64 + lane) * 8 + j] = h;
        epack[(((size_t)(ct * 2 + 1) * 2 + kt) * 64 + lane) * 8 + j] = l;
    }
}

// ---------------------------------------------------------------------------
// Pass A: MFMA scorer. Wave owns 64 rows (4 M-frags, bf16 hi/lo in VGPRs);
// loops 64 code-tiles; E staged in LDS 64KB chunks (linear copy, lane-major
// frag layout -> conflict-free ds_read_b128). 3-term dot: xh*eh + xh*el +
// xl*eh. Tracks per-lane best/sec/idx, cross-lane reduce over lane&15.
// ---------------------------------------------------------------------------
__global__ __launch_bounds__(256, 2)
void vq_fast(const float* __restrict__ x,
             const unsigned short* __restrict__ epack,
             const float* __restrict__ bsqf,
             float* __restrict__ idxout,
             int* __restrict__ amb_count,
             int* __restrict__ amb_list) {
    __shared__ unsigned short lds[32768];   // 64 KiB = 16 code-tiles

    const int t = threadIdx.x;
    const int lane = t & 63;
    const int wid = t >> 6;
    const int rowbase = (blockIdx.x * 4 + wid) * 64;
    const int arow = lane & 15;
    const int kgrp = lane >> 4;

    // A-frags: 4 M-frags x 2 k-tiles, hi+lo
    short8 ah[4][2], al[4][2];
#pragma unroll
    for (int mf = 0; mf < 4; ++mf) {
#pragma unroll
        for (int kt = 0; kt < 2; ++kt) {
            const float* src = x + (size_t)(rowbase + mf * 16 + arow) * DIM + kt * 32 + kgrp * 8;
            float4 v0 = *reinterpret_cast<const float4*>(src);
            float4 v1 = *reinterpret_cast<const float4*>(src + 4);
            float xv[8] = {v0.x, v0.y, v0.z, v0.w, v1.x, v1.y, v1.z, v1.w};
            short8 h, l;
#pragma unroll
            for (int j = 0; j < 8; ++j) {
                unsigned short hh = f2bf_rne(xv[j]);
                h[j] = (short)hh;
                l[j] = (short)f2bf_rne(xv[j] - bf2f(hh));
            }
            ah[mf][kt] = h;
            al[mf][kt] = l;
        }
    }

    float best[4][4], sec[4][4];
    int bidx[4][4];
#pragma unroll
    for (int mf = 0; mf < 4; ++mf)
#pragma unroll
        for (int r = 0; r < 4; ++r) {
            best[mf][r] = FLT_MAX; sec[mf][r] = FLT_MAX; bidx[mf][r] = 0;
        }

    for (int ch = 0; ch < 4; ++ch) {
        __syncthreads();
        {   // stage 64KB chunk: 4096 float4, 16 per thread, coalesced
            const float4* gsrc = reinterpret_cast<const float4*>(epack + (size_t)ch * 32768);
            float4* ldst = reinterpret_cast<float4*>(lds);
#pragma unroll
            for (int i = 0; i < 16; ++i)
                ldst[t + i * 256] = gsrc[t + i * 256];
        }
        __syncthreads();

        for (int ctl = 0; ctl < 16; ++ctl) {
            const int code0 = (ch * 16 + ctl) * 16;
            const unsigned short* fb = lds + ctl * 2048 + lane * 8;
            short8 bh0 = *reinterpret_cast<const short8*>(fb + 0 * 512);
            short8 bh1 = *reinterpret_cast<const short8*>(fb + 1 * 512);
            short8 bl0 = *reinterpret_cast<const short8*>(fb + 2 * 512);
            short8 bl1 = *reinterpret_cast<const short8*>(fb + 3 * 512);
            const float bq = bsqf[code0 + arow];

            f32x4 acc[4];
#pragma unroll
            for (int mf = 0; mf < 4; ++mf) {
                f32x4 a = {0.f, 0.f, 0.f, 0.f};
                a = __builtin_amdgcn_mfma_f32_16x16x32_bf16(ah[mf][0], bh0, a, 0, 0, 0);
                a = __builtin_amdgcn_mfma_f32_16x16x32_bf16(ah[mf][1], bh1, a, 0, 0, 0);
                a = __builtin_amdgcn_mfma_f32_16x16x32_bf16(ah[mf][0], bl0, a, 0, 0, 0);
                a = __builtin_amdgcn_mfma_f32_16x16x32_bf16(ah[mf][1], bl1, a, 0, 0, 0);
                a = __builtin_amdgcn_mfma_f32_16x16x32_bf16(al[mf][0], bh0, a, 0, 0, 0);
                a = __builtin_amdgcn_mfma_f32_16x16x32_bf16(al[mf][1], bh1, a, 0, 0, 0);
                acc[mf] = a;
            }

            const int code = code0 + arow;   // C col = lane&15 [m89/m91]
#pragma unroll
            for (int mf = 0; mf < 4; ++mf)
#pragma unroll
                for (int r = 0; r < 4; ++r) {
                    float s = fmaf(-2.0f, acc[mf][r], bq);
                    sec[mf][r] = fminf(sec[mf][r], fmaxf(s, best[mf][r]));
                    bidx[mf][r] = (s < best[mf][r]) ? code : bidx[mf][r];
                    best[mf][r] = fminf(best[mf][r], s);
                }
        }
    }

    // cross-lane argmin over the 16 col-classes (lane&15); row preserved
#pragma unroll
    for (int mf = 0; mf < 4; ++mf)
#pragma unroll
        for (int r = 0; r < 4; ++r) {
            float b = best[mf][r], sc = sec[mf][r];
            int id = bidx[mf][r];
#pragma unroll
            for (int off = 1; off < 16; off <<= 1) {
                float ob = __shfl_xor(b, off);
                float osc = __shfl_xor(sc, off);
                int oi = __shfl_xor(id, off);
                float nsec = fminf(fminf(sc, osc), fmaxf(b, ob));
                id = (ob < b) ? oi : id;
                b = fminf(b, ob);
                sc = nsec;
            }
            best[mf][r] = b; sec[mf][r] = sc; bidx[mf][r] = id;
        }

    if ((lane & 15) == 0) {
        const int rgrp = lane >> 4;   // C row = (lane>>4)*4 + reg [m89/m91]
#pragma unroll
        for (int mf = 0; mf < 4; ++mf)
#pragma unroll
            for (int r = 0; r < 4; ++r) {
                int row = rowbase + mf * 16 + rgrp * 4 + r;
                idxout[row] = (float)bidx[mf][r];
                if (sec[mf][r] - best[mf][r] <= TAU) {
                    int p = atomicAdd(amb_count, 1);
                    if (p < AMB_MAX) amb_list[p] = row;
                }
            }
    }
}

// ---------------------------------------------------------------------------
// Pass B: exact rescan of ambiguous rows — validated reference chain
// (np-pairwise a_sq/b_sq fp32, fp64 dot, fl32 combine, first-index ties).
// ---------------------------------------------------------------------------
__global__ void vq_exact(const float* __restrict__ x,
                         const float* __restrict__ emb,
                         const float* __restrict__ bsqf,
                         const int* __restrict__ amb_count,
                         const int* __restrict__ amb_list,
                         float* __restrict__ idxout) {
    const int lane = threadIdx.x;      // 64 lanes = 1 wave
    int cnt = *amb_count;
    if (cnt > AMB_MAX) cnt = AMB_MAX;

    for (int i = blockIdx.x; i < cnt; i += gridDim.x) {
        const int row = amb_list[i];
        float af[DIM];
        const float4* xr = reinterpret_cast<const float4*>(x + (size_t)row * DIM);
#pragma unroll
        for (int j = 0; j < DIM / 4; ++j) {
            float4 v = xr[j];
            af[j * 4 + 0] = v.x; af[j * 4 + 1] = v.y;
            af[j * 4 + 2] = v.z; af[j * 4 + 3] = v.w;
        }
        const float a_sq = np_pairwise_sq64(af);

        float best = FLT_MAX;
        int bidx = KCODES;
        for (int c = lane; c < KCODES; c += 64) {
            const float* e = emb + (size_t)c * DIM;
            double acc0 = 0.0, acc1 = 0.0, acc2 = 0.0, acc3 = 0.0;
#pragma unroll
            for (int d = 0; d < DIM; d += 4) {
                acc0 = fma((double)af[d + 0], (double)e[d + 0], acc0);
                acc1 = fma((double)af[d + 1], (double)e[d + 1], acc1);
                acc2 = fma((double)af[d + 2], (double)e[d + 2], acc2);
                acc3 = fma((double)af[d + 3], (double)e[d + 3], acc3);
            }
            double dot = (acc0 + acc1) + (acc2 + acc3);
            float ab = (float)(2.0 * dot);
            float dist = __fadd_rn(__fsub_rn(a_sq, ab), bsqf[c]);
            if (dist < best) { best = dist; bidx = c; }
        }
#pragma unroll
        for (int off = 32; off > 0; off >>= 1) {
            float ob = __shfl_xor(best, off);
            int   oi = __shfl_xor(bidx, off);
            if (ob < best || (ob == best && oi < bidx)) { best = ob; bidx = oi; }
        }
        if (lane == 0) idxout[row] = (float)bidx;
    }
}

// ---------------------------------------------------------------------------
// Pass C: finalize — gather quantized rows, histogram, deterministic loss.
// ---------------------------------------------------------------------------
__global__ __launch_bounds__(BLOCKC, 2)
void vq_finalize(const float* __restrict__ x,
                 const float* __restrict__ emb,
                 const float* __restrict__ idxout,
                 float* __restrict__ qout,
                 int* __restrict__ hist,
                 float* __restrict__ partials) {
    __shared__ float red[BLOCKC];
    const int row = blockIdx.x * BLOCKC + threadIdx.x;
    const int k = (int)idxout[row];

    const float4* xr = reinterpret_cast<const float4*>(x + (size_t)row * DIM);
    const float4* q  = reinterpret_cast<const float4*>(emb + (size_t)k * DIM);
    float4* qo = reinterpret_cast<float4*>(qout + (size_t)row * DIM);

    float lsum0 = 0.f, lsum1 = 0.f;
#pragma unroll
    for (int i = 0; i < DIM / 4; ++i) {
        float4 v = q[i];
        float4 a = xr[i];
        qo[i] = v;
        float dx = v.x - a.x, dy = v.y - a.y;
        float dz = v.z - a.z, dw = v.w - a.w;
        lsum0 = fmaf(dx, dx, lsum0);
        lsum1 = fmaf(dy, dy, lsum1);
        lsum0 = fmaf(dz, dz, lsum0);
        lsum1 = fmaf(dw, dw, lsum1);
    }
    atomicAdd(&hist[k], 1);

    __syncthreads();
    red[threadIdx.x] = lsum0 + lsum1;
    __syncthreads();
    for (int off = BLOCKC / 2; off > 0; off >>= 1) {
        if (threadIdx.x < off) red[threadIdx.x] += red[threadIdx.x + off];
        __syncthreads();
    }
    if (threadIdx.x == 0) partials[blockIdx.x] = red[0];
}

// ---------------------------------------------------------------------------
// Final: perplexity (fp64) + loss reduction.
// ---------------------------------------------------------------------------
__global__ void vq_final(const int* __restrict__ hist,
                         const float* __restrict__ partials,
                         float* __restrict__ out2) {
    __shared__ double sh[KCODES];
    __shared__ float sl[NBLOCKC];
    int t = threadIdx.x;

    double p = (double)hist[t] * (1.0 / (double)N_ROWS);
    sh[t] = p * log(p + 1e-10);
    if (t < NBLOCKC) sl[t] = partials[t];
    __syncthreads();

    for (int off = KCODES / 2; off > 0; off >>= 1) {
        if (t < off) sh[t] += sh[t + off];
        __syncthreads();
    }
    for (int off = NBLOCKC / 2; off > 0; off >>= 1) {
        if (t < off) sl[t] += sl[t + off];
        __syncthreads();
    }
    if (t == 0) {
        out2[0] = (float)exp(-sh[0]);
        out2[1] = 1.25f * sl[0] * (1.0f / (float)(N_ROWS * DIM));
    }
}

// ---------------------------------------------------------------------------
extern "C" void kernel_launch(void* const* d_in, const int* in_sizes, int n_in,
                              void* d_out, int out_size, void* d_ws, size_t ws_size,
                              hipStream_t stream) {
    const float* x   = (const float*)d_in[0];   // [131072, 64]
    const float* emb = (const float*)d_in[1];   // [1024, 64]
    float* out = (float*)d_out;

    // ws: hist[1024]@0 | bsqf[1024]@4096 | partials[512]@8192 |
    //     amb_count@10240 | amb_list[32768]@12288 | epack@143360 (256KB)
    int*   hist      = (int*)d_ws;
    float* bsqf      = (float*)((char*)d_ws + 4096);
    float* partials  = (float*)((char*)d_ws + 8192);
    int*   amb_count = (int*)((char*)d_ws + 10240);
    int*   amb_list  = (int*)((char*)d_ws + 12288);
    unsigned short* epack = (unsigned short*)((char*)d_ws + 143360);

    float* qout    = out;                       // 8388608
    float* idxout  = out + 8388608;             // 131072
    float* scalars = out + 8388608 + 131072;    // perplexity, vq_loss

    vq_prep    <<<KCODES / 256, 256, 0, stream>>>(emb, hist, bsqf, amb_count, epack);
    vq_fast    <<<N_ROWS / 256, 256, 0, stream>>>(x, epack, bsqf, idxout, amb_count, amb_list);
    vq_exact   <<<256, 64, 0, stream>>>(x, emb, bsqf, amb_count, amb_list, idxout);
    vq_finalize<<<NBLOCKC, BLOCKC, 0, stream>>>(x, emb, idxout, qout, hist, partials);
    vq_final   <<<1, KCODES, 0, stream>>>(hist, partials, scalars);
}